// Round 8
// baseline (110.378 us; speedup 1.0000x reference)
//
#include <hip/hip_runtime.h>

// DeformConv2dBlock on gfx950: B=8, C=64, H=W=128, N=9 taps, pad=1.
// R7: R6 (2-row blocks, 5-slot ring, 3 blocks/CU) with the rowbase double-add
// bug fixed (rowbase = h+rr; TAPR adds the kernel-row term g exactly once).

typedef _Float16 h2    __attribute__((ext_vector_type(2)));
typedef _Float16 f16x8 __attribute__((ext_vector_type(8)));
typedef float    f32x4 __attribute__((ext_vector_type(4)));

#define MFMAH(a, b, c) __builtin_amdgcn_mfma_f32_16x16x32_f16(a, b, c, 0, 0, 0)

__device__ __forceinline__ unsigned short f2h(float f) {
    return __builtin_bit_cast(unsigned short, (_Float16)f);
}
__device__ __forceinline__ float h2f_bits(unsigned u) {
    return (float)__builtin_bit_cast(_Float16, (unsigned short)(u & 0xffffu));
}
__device__ __forceinline__ unsigned dup16(float g) {
    _Float16 t = (_Float16)g;
    h2 r = {t, t};
    return __builtin_bit_cast(unsigned, r);
}

// x[b][c][h][w] f32 -> xt[b][h][w][c] fp16
__global__ __launch_bounds__(256) void k_prep_xt(const float* __restrict__ x,
                                                 unsigned short* __restrict__ xt) {
    __shared__ float xs[64][129];
    const int bh = blockIdx.x;
    const int h = bh & 127, b = bh >> 7;
    const float* xr = x + ((size_t)b * 64 * 128 + h) * 128;
    for (int idx = threadIdx.x; idx < 8192; idx += 256) {
        int c = idx >> 7, w = idx & 127;
        xs[c][w] = xr[(size_t)c * 16384 + w];
    }
    __syncthreads();
    unsigned short* xto = xt + ((size_t)bh << 13);
    for (int j = threadIdx.x; j < 1024; j += 256) {
        int w = j >> 3, c0 = (j & 7) << 3;
        unsigned short tmp[8];
#pragma unroll
        for (int e = 0; e < 8; ++e) tmp[e] = f2h(xs[c0 + e][w]);
        *(uint4*)(xto + w * 64 + c0) = *(const uint4*)tmp;
    }
}

// Fragment-ordered fp16 weights (layout as R3/R4/R5).
__global__ void k_prep_w(const float* __restrict__ w_conv, const float* __restrict__ w_off,
                         unsigned short* __restrict__ w_m2, unsigned short* __restrict__ woff2) {
    int t = blockIdx.x * 256 + threadIdx.x;
    if (t < 36864) {
        int r = t & 511;
        int fid = t >> 9;
        int l15 = r >> 5, q4 = (r >> 3) & 3, e = t & 7;
        int chunk = fid & 1, of = (fid >> 1) & 3, n = fid >> 3;
        int o = of * 16 + l15, c = chunk * 32 + q4 * 8 + e;
        w_m2[t] = f2h(w_conv[(o * 64 + c) * 9 + n]);
    }
    int t2 = t - 36864;
    if (t2 >= 0 && t2 < 18432) {
        int r = t2 & 511;
        int fid = t2 >> 9;
        int l15 = r >> 5, q4 = (r >> 3) & 3, e = t2 & 7;
        int kc = fid & 1, half = (fid >> 1) & 1, rj = fid >> 2;
        int k = half * 16 + l15, c = kc * 32 + q4 * 8 + e;
        woff2[t2] = (k < 18) ? f2h(w_off[(k * 64 + c) * 9 + rj]) : (unsigned short)0;
    }
}

// One block = (b, hpair, wt): 2 rows x 64 px x 64 outputs. 4 waves.
__global__ __launch_bounds__(256, 3) void k_fused(
    const float* __restrict__ x, const unsigned short* __restrict__ xt,
    const unsigned short* __restrict__ w_m2, const unsigned short* __restrict__ woff2,
    const float* __restrict__ b_off, float* __restrict__ out) {

    __shared__ __align__(16) unsigned char raw[5 * 70 * 128];   // 5-slot row ring, swizzled
    __shared__ __align__(16) _Float16 offv[2][64][24];          // per row: 0..8 ox, 9..17 oy
    __shared__ int sfb;

    const int wk = ((blockIdx.x & 7) << 7) | (blockIdx.x >> 3);   // XCD: one image per XCD
    const int b = wk >> 7, h = ((wk >> 1) & 63) << 1, wt = (wk & 1) << 6;

    const int tid  = threadIdx.x;
    const int lane = tid & 63, wid = tid >> 6;
    const int l15  = lane & 15, q4 = lane >> 4;
    const int lofs = ((l15 << 2) + q4) << 3;
    const int px   = wid * 16 + l15;

    const unsigned short* xtb = xt + ((size_t)b << 20);
    const _Float16* wmh  = (const _Float16*)w_m2;

    if (tid == 0) sfb = 0;

    // ---- initial staging: unpadded rows h-2..h+2 -> slots 0..4 ----
    for (int idx = tid; idx < 2800; idx += 256) {
        int rec = idx >> 3, cc = idx & 7;
        int rl = rec / 70, col = rec - rl * 70;
        int xr = h - 2 + rl, xc = wt - 3 + col;
        uint4 v = make_uint4(0, 0, 0, 0);
        if (xr >= 0 && xr < 128 && xc >= 0 && xc < 128)
            v = *(const uint4*)(xtb + ((((size_t)xr << 7) + xc) << 6) + (cc << 3));
        *(uint4*)(raw + (rec << 7) + ((cc ^ (col & 7)) << 4)) = v;
    }
    __syncthreads();

    // ---- Phase A: offset conv via fp16 MFMA, rows h and h+1 ----
#pragma unroll
    for (int rr = 0; rr < 2; ++rr) {
        f32x4 o0 = {0.f, 0.f, 0.f, 0.f}, o1 = {0.f, 0.f, 0.f, 0.f};
#pragma unroll
        for (int rj = 0; rj < 9; ++rj) {
            const int dr = rj / 3, dj = rj % 3;
            const int colw = px + dj + 2;
            const int recb = (rr + dr + 1) * 70 + colw;   // slot = rr+dr+1
            const int swz  = colw & 7;
#pragma unroll
            for (int kc = 0; kc < 2; ++kc) {
                f16x8 bfrag = *(const f16x8*)(raw + (recb << 7) + ((((kc << 2) + q4) ^ swz) << 4));
                f16x8 a0 = *(const f16x8*)((const _Float16*)woff2 + ((((rj * 2 + 0) << 1) + kc) << 9) + lofs);
                f16x8 a1 = *(const f16x8*)((const _Float16*)woff2 + ((((rj * 2 + 1) << 1) + kc) << 9) + lofs);
                o0 = MFMAH(a0, bfrag, o0);
                o1 = MFMAH(a1, bfrag, o1);
            }
        }
        float4 bo = *(const float4*)(b_off + (q4 << 2));
        float2 bo2 = *(const float2*)(b_off + 16);
        const float bov[4] = {bo.x, bo.y, bo.z, bo.w};
#pragma unroll
        for (int rg = 0; rg < 4; ++rg) {
            int o = (q4 << 2) + rg;
            offv[rr][px][o] = (_Float16)(o0[rg] + bov[rg]);
            if (q4 == 0 && rg < 2) offv[rr][px][16 + rg] = (_Float16)(o1[rg] + (rg ? bo2.y : bo2.x));
        }
    }
    __syncthreads();

    // ---- Phase B-lite: flag if any corner leaves its dr-group ring window ----
    for (int idx = tid; idx < 1152; idx += 256) {
        const int p = idx & 63;
        int rest = idx >> 6;                 // 0..17
        const int rr = (rest >= 9) ? 1 : 0;
        const int n = rest - rr * 9;
        const int g = n / 3, dj = n % 3;
        float ox = (float)offv[rr][p][n], oy = (float)offv[rr][p][9 + n];
        float pxf = (float)(h + rr + g) + ox, pyf = (float)(wt + p + dj) + oy;
        float fx = floorf(pxf), fy = floorf(pyf);
        int qx0 = (int)fminf(fmaxf(fx, 0.f), 129.f);
        int qx1 = (int)fminf(fmaxf(fx + 1.f, 0.f), 129.f);
        int qy0 = (int)fminf(fmaxf(fy, 0.f), 129.f);
        int qy1 = (int)fminf(fmaxf(fy + 1.f, 0.f), 129.f);
        int t0 = qx0 + 1 - h - g, t1 = qx1 + 1 - h - g;      // ring rows [0,4]
        int c0 = qy0 - wt + 2, c1 = qy1 - wt + 2;            // cols [0,69]
        bool oow = ((unsigned)t0 > 4u) | ((unsigned)t1 > 4u) |
                   ((unsigned)c0 > 69u) | ((unsigned)c1 > 69u);
        if (oow) sfb = 1;
    }
    __syncthreads();
    const bool slow = (sfb != 0);

    f32x4 acc0[4], acc1[4];
#pragma unroll
    for (int of = 0; of < 4; ++of) {
        acc0[of] = (f32x4){0.f, 0.f, 0.f, 0.f};
        acc1[of] = (f32x4){0.f, 0.f, 0.f, 0.f};
    }

    auto blend = [&](const uint4* clo, const uint4* chi, uint4 gq, f16x8& bfr0, f16x8& bfr1) {
        h2 g0 = __builtin_bit_cast(h2, gq.x), g1 = __builtin_bit_cast(h2, gq.y);
        h2 g2 = __builtin_bit_cast(h2, gq.z), g3 = __builtin_bit_cast(h2, gq.w);
        const unsigned* c0 = (const unsigned*)&clo[0];
        const unsigned* c1 = (const unsigned*)&clo[1];
        const unsigned* c2 = (const unsigned*)&clo[2];
        const unsigned* c3 = (const unsigned*)&clo[3];
        const unsigned* e0 = (const unsigned*)&chi[0];
        const unsigned* e1 = (const unsigned*)&chi[1];
        const unsigned* e2 = (const unsigned*)&chi[2];
        const unsigned* e3 = (const unsigned*)&chi[3];
        unsigned owl[4], owh[4];
#pragma unroll
        for (int d = 0; d < 4; ++d) {
            h2 sl = __builtin_bit_cast(h2, c0[d]) * g0;
            sl = __builtin_elementwise_fma(__builtin_bit_cast(h2, c1[d]), g1, sl);
            sl = __builtin_elementwise_fma(__builtin_bit_cast(h2, c2[d]), g2, sl);
            sl = __builtin_elementwise_fma(__builtin_bit_cast(h2, c3[d]), g3, sl);
            owl[d] = __builtin_bit_cast(unsigned, sl);
            h2 sh = __builtin_bit_cast(h2, e0[d]) * g0;
            sh = __builtin_elementwise_fma(__builtin_bit_cast(h2, e1[d]), g1, sh);
            sh = __builtin_elementwise_fma(__builtin_bit_cast(h2, e2[d]), g2, sh);
            sh = __builtin_elementwise_fma(__builtin_bit_cast(h2, e3[d]), g3, sh);
            owh[d] = __builtin_bit_cast(unsigned, sh);
        }
        bfr0 = __builtin_bit_cast(f16x8, *(const uint4*)owl);
        bfr1 = __builtin_bit_cast(f16x8, *(const uint4*)owh);
    };

    if (!slow) {
        // ---- preload both rows' offsets into const-indexed regs ----
        const unsigned* op0 = (const unsigned*)&offv[0][px][0];
        const unsigned* op1 = (const unsigned*)&offv[1][px][0];
        uint4 oA0 = *(const uint4*)op0, oB0 = *(const uint4*)(op0 + 4);
        unsigned oC0 = op0[8];
        uint4 oA1 = *(const uint4*)op1, oB1 = *(const uint4*)(op1 + 4);
        unsigned oC1 = op1[8];
        const unsigned ow0[9] = {oA0.x, oA0.y, oA0.z, oA0.w, oB0.x, oB0.y, oB0.z, oB0.w, oC0};
        const unsigned ow1[9] = {oA1.x, oA1.y, oA1.z, oA1.w, oB1.x, oB1.y, oB1.z, oB1.w, oC1};
#define OXQ(arr, n) h2f_bits(arr[(n) >> 1] >> (((n) & 1) << 4))
#define OYQ(arr, n) h2f_bits(arr[(9 + (n)) >> 1] >> (((9 + (n)) & 1) << 4))

        // ---- prefetch row h+3 into regs (ring slot 0 after dr-group 0) ----
        uint4 pf[3];
        int pcol[3], pcc[3];
#pragma unroll
        for (int k = 0; k < 3; ++k) {
            int idx = tid + (k << 8);
            bool v = idx < 560;
            int rec = idx >> 3;
            pcc[k] = idx & 7;
            int xr = h + 3, xc = wt - 3 + rec;
            uint4 vv = make_uint4(0, 0, 0, 0);
            if (v && xr < 128 && xc >= 0 && xc < 128)
                vv = *(const uint4*)(xtb + ((((size_t)xr << 7) + xc) << 6) + (pcc[k] << 3));
            pcol[k] = v ? rec : -1;
            pf[k] = vv;
        }

        // one row of one tap: corner math -> 8 swizzled ds_reads -> blend -> 8 MFMA
        // rowbase = h+rr (base output row); the kernel-row term g is added HERE, once.
#define TAPR(n, OWA, ACC)                                                                \
        {                                                                                \
            constexpr int g = (n) / 3, dj = (n) % 3;                                     \
            float ox = OXQ(OWA, n), oy = OYQ(OWA, n);                                    \
            float pxf = rowbase + (float)g + ox, pyf = (float)(wt + px + dj) + oy;       \
            float fx = floorf(pxf), fy = floorf(pyf);                                    \
            float qx0f = fminf(fmaxf(fx, 0.f), 129.f);                                   \
            float qx1f = fminf(fmaxf(fx + 1.f, 0.f), 129.f);                             \
            float qy0f = fminf(fmaxf(fy, 0.f), 129.f);                                   \
            float qy1f = fminf(fmaxf(fy + 1.f, 0.f), 129.f);                             \
            float pxc = fminf(fmaxf(pxf, 0.f), 129.f);                                   \
            float pyc = fminf(fmaxf(pyf, 0.f), 129.f);                                   \
            float ax0 = 1.f + (qx0f - pxc), ax1 = 1.f - (qx1f - pxc);                    \
            float ay0 = 1.f + (qy0f - pyc), ay1 = 1.f - (qy1f - pyc);                    \
            int u0 = (int)qx0f + 1 - h, u1 = (int)qx1f + 1 - h;                          \
            int s0 = (u0 - (u0 >= 5 ? 5 : 0)) * 70;                                      \
            int s1 = (u1 - (u1 >= 5 ? 5 : 0)) * 70;                                      \
            int c0 = (int)qy0f - wt + 2, c1 = (int)qy1f - wt + 2;                        \
            int blt = (s0 + c0) << 7, brb = (s1 + c1) << 7;                              \
            int blb = (s0 + c1) << 7, brt = (s1 + c0) << 7;                              \
            int z0 = ((q4 ^ c0) & 7) << 4, z1 = ((q4 ^ c1) & 7) << 4;                    \
            uint4 clo[4], chi[4];                                                        \
            clo[0] = *(const uint4*)(raw + blt + z0); chi[0] = *(const uint4*)(raw + blt + (z0 ^ 64)); \
            clo[1] = *(const uint4*)(raw + brb + z1); chi[1] = *(const uint4*)(raw + brb + (z1 ^ 64)); \
            clo[2] = *(const uint4*)(raw + blb + z1); chi[2] = *(const uint4*)(raw + blb + (z1 ^ 64)); \
            clo[3] = *(const uint4*)(raw + brt + z0); chi[3] = *(const uint4*)(raw + brt + (z0 ^ 64)); \
            uint4 gq = make_uint4(dup16(ax0 * ay0), dup16(ax1 * ay1),                    \
                                  dup16(ax0 * ay1), dup16(ax1 * ay0));                   \
            f16x8 bfr0, bfr1;                                                            \
            blend(clo, chi, gq, bfr0, bfr1);                                             \
            _Pragma("unroll")                                                            \
            for (int of = 0; of < 4; ++of) {                                             \
                ACC[of] = MFMAH(wa0[of], bfr0, ACC[of]);                                 \
                ACC[of] = MFMAH(wa1[of], bfr1, ACC[of]);                                 \
            }                                                                            \
        }

#define TAP(n)                                                                           \
        {                                                                                \
            const _Float16* wn = wmh + ((n) << 12);                                      \
            f16x8 wa0[4], wa1[4];                                                        \
            _Pragma("unroll")                                                            \
            for (int of = 0; of < 4; ++of) {                                             \
                wa0[of] = *(const f16x8*)(wn + (((of << 1) + 0) << 9) + lofs);           \
                wa1[of] = *(const f16x8*)(wn + (((of << 1) + 1) << 9) + lofs);           \
            }                                                                            \
            { const float rowbase = (float)h;       TAPR(n, ow0, acc0) }                 \
            { const float rowbase = (float)(h + 1); TAPR(n, ow1, acc1) }                 \
        }

        TAP(0) TAP(1) TAP(2)
        __syncthreads();
#pragma unroll
        for (int k = 0; k < 3; ++k)
            if (pcol[k] >= 0)
                *(uint4*)(raw + ((0 * 70 + pcol[k]) << 7) + ((pcc[k] ^ (pcol[k] & 7)) << 4)) = pf[k];
        __syncthreads();
        // prefetch row h+4 (slot 1) during dr-group 1
#pragma unroll
        for (int k = 0; k < 3; ++k) {
            int idx = tid + (k << 8);
            bool v = idx < 560;
            int rec = idx >> 3;
            pcc[k] = idx & 7;
            int xr = h + 4, xc = wt - 3 + rec;
            uint4 vv = make_uint4(0, 0, 0, 0);
            if (v && xr < 128 && xc >= 0 && xc < 128)
                vv = *(const uint4*)(xtb + ((((size_t)xr << 7) + xc) << 6) + (pcc[k] << 3));
            pcol[k] = v ? rec : -1;
            pf[k] = vv;
        }
        TAP(3) TAP(4) TAP(5)
        __syncthreads();
#pragma unroll
        for (int k = 0; k < 3; ++k)
            if (pcol[k] >= 0)
                *(uint4*)(raw + ((1 * 70 + pcol[k]) << 7) + ((pcc[k] ^ (pcol[k] & 7)) << 4)) = pf[k];
        __syncthreads();
        TAP(6) TAP(7) TAP(8)
#undef TAP
#undef TAPR
#undef OXQ
#undef OYQ
    } else {
        // ---- SLOW PATH (rare): all-global gather for both rows ----
        for (int rr = 0; rr < 2; ++rr) {
            f32x4* ACC = rr ? acc1 : acc0;
            for (int n = 0; n < 9; ++n) {
                const int g = n / 3, dj = n % 3;
                float ox = (float)offv[rr][px][n], oy = (float)offv[rr][px][9 + n];
                float pxf = (float)(h + rr + g) + ox, pyf = (float)(wt + px + dj) + oy;
                float fx = floorf(pxf), fy = floorf(pyf);
                float qx0f = fminf(fmaxf(fx, 0.f), 129.f);
                float qx1f = fminf(fmaxf(fx + 1.f, 0.f), 129.f);
                float qy0f = fminf(fmaxf(fy, 0.f), 129.f);
                float qy1f = fminf(fmaxf(fy + 1.f, 0.f), 129.f);
                float pxc = fminf(fmaxf(pxf, 0.f), 129.f);
                float pyc = fminf(fmaxf(pyf, 0.f), 129.f);
                float ax0 = 1.f + (qx0f - pxc), ax1 = 1.f - (qx1f - pxc);
                float ay0 = 1.f + (qy0f - pyc), ay1 = 1.f - (qy1f - pyc);
                int qx[2] = {(int)qx0f, (int)qx1f};
                int qy[2] = {(int)qy0f, (int)qy1f};
                uint4 clo[4], chi[4];
                const int rsel[4] = {0, 1, 0, 1}, csel[4] = {0, 1, 1, 0};
#pragma unroll
                for (int j = 0; j < 4; ++j) {
                    int rx = qx[rsel[j]], ry = qy[csel[j]];
                    bool v = (rx >= 1) & (rx <= 128) & (ry >= 1) & (ry <= 128);
                    clo[j] = make_uint4(0, 0, 0, 0);
                    chi[j] = make_uint4(0, 0, 0, 0);
                    if (v) {
                        const unsigned short* gp = xtb + ((((size_t)(rx - 1) << 7) + (ry - 1)) << 6);
                        clo[j] = *(const uint4*)(gp + (q4 << 3));
                        chi[j] = *(const uint4*)(gp + (q4 << 3) + 32);
                    }
                }
                uint4 gq = make_uint4(dup16(ax0 * ay0), dup16(ax1 * ay1),
                                      dup16(ax0 * ay1), dup16(ax1 * ay0));
                f16x8 bfr0, bfr1;
                blend(clo, chi, gq, bfr0, bfr1);
                const _Float16* wn = wmh + (n << 12);
#pragma unroll
                for (int of = 0; of < 4; ++of) {
                    f16x8 a0 = *(const f16x8*)(wn + (((of << 1) + 0) << 9) + lofs);
                    f16x8 a1 = *(const f16x8*)(wn + (((of << 1) + 1) << 9) + lofs);
                    ACC[of] = MFMAH(a0, bfr0, ACC[of]);
                    ACC[of] = MFMAH(a1, bfr1, ACC[of]);
                }
            }
        }
    }

    // ---- Epilogue: + residual, both rows ----
    const size_t obase = ((size_t)b * 64 * 128 + h) * 128 + wt + px;
#pragma unroll
    for (int of = 0; of < 4; ++of)
#pragma unroll
        for (int rg = 0; rg < 4; ++rg) {
            size_t a = obase + (size_t)((of << 4) + (q4 << 2) + rg) * 16384;
            out[a] = acc0[of][rg] + x[a];
            out[a + 128] = acc1[of][rg] + x[a + 128];
        }
}

extern "C" void kernel_launch(void* const* d_in, const int* in_sizes, int n_in,
                              void* d_out, int out_size, void* d_ws, size_t ws_size,
                              hipStream_t stream) {
    const float* x      = (const float*)d_in[0];
    const float* w_off  = (const float*)d_in[1];
    const float* b_off  = (const float*)d_in[2];
    const float* w_conv = (const float*)d_in[3];

    unsigned short* xt    = (unsigned short*)d_ws;
    unsigned short* w_m2  = xt + (size_t)8 * 128 * 128 * 64;
    unsigned short* woff2 = w_m2 + 9 * 64 * 64;

    hipLaunchKernelGGL(k_prep_xt, dim3(1024), dim3(256), 0, stream, x, xt);
    hipLaunchKernelGGL(k_prep_w,  dim3(216),  dim3(256), 0, stream, w_conv, w_off, w_m2, woff2);
    hipLaunchKernelGGL(k_fused,   dim3(1024), dim3(256), 0, stream,
                       x, xt, w_m2, woff2, b_off, (float*)d_out);
}

// Round 9
// 91.597 us; speedup vs baseline: 1.2050x; 1.2050x over previous
//
#include <hip/hip_runtime.h>

// DeformConv2dBlock on gfx950: B=8, C=64, H=W=128, N=9 taps, pad=1.
// R8: explicit depth-1 software pipeline (named A/B buffers) for corners+weights,
// static 6-row window, barrier-free tap loop, reg-held offsets, (256,2) VGPR room.

typedef _Float16 h2    __attribute__((ext_vector_type(2)));
typedef _Float16 f16x8 __attribute__((ext_vector_type(8)));
typedef float    f32x4 __attribute__((ext_vector_type(4)));

#define MFMAH(a, b, c) __builtin_amdgcn_mfma_f32_16x16x32_f16(a, b, c, 0, 0, 0)

__device__ __forceinline__ unsigned short f2h(float f) {
    return __builtin_bit_cast(unsigned short, (_Float16)f);
}
__device__ __forceinline__ float h2f_bits(unsigned u) {
    return (float)__builtin_bit_cast(_Float16, (unsigned short)(u & 0xffffu));
}
__device__ __forceinline__ unsigned dup16(float g) {
    _Float16 t = (_Float16)g;
    h2 r = {t, t};
    return __builtin_bit_cast(unsigned, r);
}

__device__ __forceinline__ void blend8(const uint4* clo, const uint4* chi, uint4 gq,
                                       f16x8& bfr0, f16x8& bfr1) {
    h2 g0 = __builtin_bit_cast(h2, gq.x), g1 = __builtin_bit_cast(h2, gq.y);
    h2 g2 = __builtin_bit_cast(h2, gq.z), g3 = __builtin_bit_cast(h2, gq.w);
    const unsigned* c0 = (const unsigned*)&clo[0];
    const unsigned* c1 = (const unsigned*)&clo[1];
    const unsigned* c2 = (const unsigned*)&clo[2];
    const unsigned* c3 = (const unsigned*)&clo[3];
    const unsigned* e0 = (const unsigned*)&chi[0];
    const unsigned* e1 = (const unsigned*)&chi[1];
    const unsigned* e2 = (const unsigned*)&chi[2];
    const unsigned* e3 = (const unsigned*)&chi[3];
    unsigned owl[4], owh[4];
#pragma unroll
    for (int d = 0; d < 4; ++d) {
        h2 sl = __builtin_bit_cast(h2, c0[d]) * g0;
        sl = __builtin_elementwise_fma(__builtin_bit_cast(h2, c1[d]), g1, sl);
        sl = __builtin_elementwise_fma(__builtin_bit_cast(h2, c2[d]), g2, sl);
        sl = __builtin_elementwise_fma(__builtin_bit_cast(h2, c3[d]), g3, sl);
        owl[d] = __builtin_bit_cast(unsigned, sl);
        h2 sh = __builtin_bit_cast(h2, e0[d]) * g0;
        sh = __builtin_elementwise_fma(__builtin_bit_cast(h2, e1[d]), g1, sh);
        sh = __builtin_elementwise_fma(__builtin_bit_cast(h2, e2[d]), g2, sh);
        sh = __builtin_elementwise_fma(__builtin_bit_cast(h2, e3[d]), g3, sh);
        owh[d] = __builtin_bit_cast(unsigned, sh);
    }
    bfr0 = __builtin_bit_cast(f16x8, *(const uint4*)owl);
    bfr1 = __builtin_bit_cast(f16x8, *(const uint4*)owh);
}

// x[b][c][h][w] f32 -> xt[b][h][w][c] fp16
__global__ __launch_bounds__(256) void k_prep_xt(const float* __restrict__ x,
                                                 unsigned short* __restrict__ xt) {
    __shared__ float xs[64][129];
    const int bh = blockIdx.x;
    const int h = bh & 127, b = bh >> 7;
    const float* xr = x + ((size_t)b * 64 * 128 + h) * 128;
    for (int idx = threadIdx.x; idx < 8192; idx += 256) {
        int c = idx >> 7, w = idx & 127;
        xs[c][w] = xr[(size_t)c * 16384 + w];
    }
    __syncthreads();
    unsigned short* xto = xt + ((size_t)bh << 13);
    for (int j = threadIdx.x; j < 1024; j += 256) {
        int w = j >> 3, c0 = (j & 7) << 3;
        unsigned short tmp[8];
#pragma unroll
        for (int e = 0; e < 8; ++e) tmp[e] = f2h(xs[c0 + e][w]);
        *(uint4*)(xto + w * 64 + c0) = *(const uint4*)tmp;
    }
}

// Fragment-ordered fp16 weights (layout as R3..R7).
__global__ void k_prep_w(const float* __restrict__ w_conv, const float* __restrict__ w_off,
                         unsigned short* __restrict__ w_m2, unsigned short* __restrict__ woff2) {
    int t = blockIdx.x * 256 + threadIdx.x;
    if (t < 36864) {
        int r = t & 511;
        int fid = t >> 9;
        int l15 = r >> 5, q4 = (r >> 3) & 3, e = t & 7;
        int chunk = fid & 1, of = (fid >> 1) & 3, n = fid >> 3;
        int o = of * 16 + l15, c = chunk * 32 + q4 * 8 + e;
        w_m2[t] = f2h(w_conv[(o * 64 + c) * 9 + n]);
    }
    int t2 = t - 36864;
    if (t2 >= 0 && t2 < 18432) {
        int r = t2 & 511;
        int fid = t2 >> 9;
        int l15 = r >> 5, q4 = (r >> 3) & 3, e = t2 & 7;
        int kc = fid & 1, half = (fid >> 1) & 1, rj = fid >> 2;
        int k = half * 16 + l15, c = kc * 32 + q4 * 8 + e;
        woff2[t2] = (k < 18) ? f2h(w_off[(k * 64 + c) * 9 + rj]) : (unsigned short)0;
    }
}

// One block = (b, h, wt): 64 pixels x 64 output channels. 4 waves.
__global__ __launch_bounds__(256, 2) void k_fused(
    const float* __restrict__ x, const unsigned short* __restrict__ xt,
    const unsigned short* __restrict__ w_m2, const unsigned short* __restrict__ woff2,
    const float* __restrict__ b_off, float* __restrict__ out) {

    __shared__ __align__(16) unsigned char raw[6 * 70 * 128];   // rows h-2..h+3, swizzled, zero-filled
    __shared__ __align__(16) _Float16 offv[64 * 24];            // 0..8 ox, 9..17 oy (fp16)
    __shared__ int sfb;

    const int wk = ((blockIdx.x & 7) << 8) + (blockIdx.x >> 3);   // XCD swizzle (2048 grid, bijective)
    const int b = wk >> 8, h = (wk >> 1) & 127, wt = (wk & 1) << 6;

    const int tid  = threadIdx.x;
    const int lane = tid & 63, wid = tid >> 6;
    const int l15  = lane & 15, q4 = lane >> 4;
    const int lofs = ((l15 << 2) + q4) << 3;
    const int px   = wid * 16 + l15;

    const unsigned short* xtb = xt + ((size_t)b << 20);
    const _Float16* wmh  = (const _Float16*)w_m2;
    const _Float16* wofh = (const _Float16*)woff2;

    if (tid == 0) sfb = 0;

    // ---- stage static window: rows h-2..h+3, cols wt-3..wt+66, zero-filled, swizzled ----
    for (int idx = tid; idx < 3360; idx += 256) {
        int rec = idx >> 3, cc = idx & 7;
        int rl = rec / 70, col = rec - rl * 70;
        int xr = h - 2 + rl, xc = wt - 3 + col;
        uint4 v = make_uint4(0, 0, 0, 0);
        if (xr >= 0 && xr < 128 && xc >= 0 && xc < 128)
            v = *(const uint4*)(xtb + ((((size_t)xr << 7) + xc) << 6) + (cc << 3));
        *(uint4*)(raw + (rec << 7) + ((cc ^ (col & 7)) << 4)) = v;
    }
    __syncthreads();

    // ---- Phase A: offset conv via fp16 MFMA, depth-1 pipelined, split accumulators ----
    {
        f32x4 o0a = {0,0,0,0}, o0b = {0,0,0,0}, o1a = {0,0,0,0}, o1b = {0,0,0,0};
        f16x8 bfgA, af0A, af1A, bfgB, af0B, af1B;

#define ALOAD(s, S)                                                                      \
        {                                                                                \
            constexpr int rj = (s) >> 1, kc = (s) & 1;                                   \
            const int colw = px + (rj % 3) + 2;                                          \
            const int recb = ((rj / 3) + 1) * 70 + colw;                                 \
            bfg##S = *(const f16x8*)(raw + (recb << 7) + ((((kc << 2) + q4) ^ (colw & 7)) << 4)); \
            af0##S = *(const f16x8*)(wofh + ((((rj * 2 + 0) << 1) + kc) << 9) + lofs);   \
            af1##S = *(const f16x8*)(wofh + ((((rj * 2 + 1) << 1) + kc) << 9) + lofs);   \
        }
#define AEXEC(S, P)                                                                      \
        {                                                                                \
            o0##P = MFMAH(af0##S, bfg##S, o0##P);                                        \
            o1##P = MFMAH(af1##S, bfg##S, o1##P);                                        \
        }
        ALOAD(0, A)
        ALOAD(1, B)  AEXEC(A, a)
        ALOAD(2, A)  AEXEC(B, b)
        ALOAD(3, B)  AEXEC(A, a)
        ALOAD(4, A)  AEXEC(B, b)
        ALOAD(5, B)  AEXEC(A, a)
        ALOAD(6, A)  AEXEC(B, b)
        ALOAD(7, B)  AEXEC(A, a)
        ALOAD(8, A)  AEXEC(B, b)
        ALOAD(9, B)  AEXEC(A, a)
        ALOAD(10, A) AEXEC(B, b)
        ALOAD(11, B) AEXEC(A, a)
        ALOAD(12, A) AEXEC(B, b)
        ALOAD(13, B) AEXEC(A, a)
        ALOAD(14, A) AEXEC(B, b)
        ALOAD(15, B) AEXEC(A, a)
        ALOAD(16, A) AEXEC(B, b)
        ALOAD(17, B) AEXEC(A, a)
                     AEXEC(B, b)
#undef ALOAD
#undef AEXEC
        f32x4 o0, o1;
#pragma unroll
        for (int rg = 0; rg < 4; ++rg) { o0[rg] = o0a[rg] + o0b[rg]; o1[rg] = o1a[rg] + o1b[rg]; }
        float4 bo = *(const float4*)(b_off + (q4 << 2));
        float2 bo2 = *(const float2*)(b_off + 16);
        const float bov[4] = {bo.x, bo.y, bo.z, bo.w};
#pragma unroll
        for (int rg = 0; rg < 4; ++rg) {
            int o = (q4 << 2) + rg;
            offv[px * 24 + o] = (_Float16)(o0[rg] + bov[rg]);
            if (q4 == 0 && rg < 2) offv[px * 24 + 16 + rg] = (_Float16)(o1[rg] + (rg ? bo2.y : bo2.x));
        }
    }
    __syncthreads();

    // ---- Phase B-lite: flag any corner outside the static window (identical FP math) ----
    for (int idx = tid; idx < 576; idx += 256) {
        const int n = idx >> 6, p = idx & 63;
        const int g = n / 3, dj = n % 3;
        float ox = (float)offv[p * 24 + n], oy = (float)offv[p * 24 + 9 + n];
        float pxf = (float)(h + g) + ox, pyf = (float)(wt + p + dj) + oy;
        float fx = floorf(pxf), fy = floorf(pyf);
        int wr0 = (int)fminf(fmaxf(fx, 0.f), 129.f) + 1 - h;
        int wr1 = (int)fminf(fmaxf(fx + 1.f, 0.f), 129.f) + 1 - h;
        int c0 = (int)fminf(fmaxf(fy, 0.f), 129.f) - wt + 2;
        int c1 = (int)fminf(fmaxf(fy + 1.f, 0.f), 129.f) - wt + 2;
        bool oow = ((unsigned)wr0 > 5u) | ((unsigned)wr1 > 5u) |
                   ((unsigned)c0 > 69u) | ((unsigned)c1 > 69u);
        if (oow) sfb = 1;
    }
    __syncthreads();
    const bool slow = (sfb != 0);

    // ---- residual prefetch (stays outstanding under the tap loop) ----
    const size_t obase = ((size_t)b * 64 * 128 + h) * 128 + wt + px;
    float xres[4][4];
#pragma unroll
    for (int of = 0; of < 4; ++of)
#pragma unroll
        for (int rg = 0; rg < 4; ++rg)
            xres[of][rg] = x[obase + (size_t)((of << 4) + (q4 << 2) + rg) * 16384];

    f32x4 acc[4];
#pragma unroll
    for (int of = 0; of < 4; ++of) acc[of] = (f32x4){0.f, 0.f, 0.f, 0.f};

    if (!slow) {
        // ---- preload my pixel's 18 offsets to const-indexed regs ----
        const unsigned* op = (const unsigned*)(offv + px * 24);
        uint4 oA = *(const uint4*)op;
        uint4 oB = *(const uint4*)(op + 4);
        unsigned oC = op[8];
        const unsigned owr[9] = {oA.x, oA.y, oA.z, oA.w, oB.x, oB.y, oB.z, oB.w, oC};
#define OXQ(n) h2f_bits(owr[(n) >> 1] >> (((n) & 1) << 4))
#define OYQ(n) h2f_bits(owr[(9 + (n)) >> 1] >> (((9 + (n)) & 1) << 4))

        // pipeline buffers (named, compile-time indexed only)
        uint4 cloA[4], chiA[4], cloB[4], chiB[4];
        uint4 gqA, gqB;
        f16x8 waA[8], waB[8];

#define TAPLOAD(n, S)                                                                    \
        {                                                                                \
            constexpr int g = (n) / 3, dj = (n) % 3;                                     \
            float ox = OXQ(n), oy = OYQ(n);                                              \
            float pxf = (float)(h + g) + ox, pyf = (float)(wt + px + dj) + oy;           \
            float fx = floorf(pxf), fy = floorf(pyf);                                    \
            float qx0f = fminf(fmaxf(fx, 0.f), 129.f);                                   \
            float qx1f = fminf(fmaxf(fx + 1.f, 0.f), 129.f);                             \
            float qy0f = fminf(fmaxf(fy, 0.f), 129.f);                                   \
            float qy1f = fminf(fmaxf(fy + 1.f, 0.f), 129.f);                             \
            float pxc = fminf(fmaxf(pxf, 0.f), 129.f);                                   \
            float pyc = fminf(fmaxf(pyf, 0.f), 129.f);                                   \
            float ax0 = 1.f + (qx0f - pxc), ax1 = 1.f - (qx1f - pxc);                    \
            float ay0 = 1.f + (qy0f - pyc), ay1 = 1.f - (qy1f - pyc);                    \
            int r0 = ((int)qx0f + 1 - h) * 70, r1 = ((int)qx1f + 1 - h) * 70;            \
            int c0 = (int)qy0f - wt + 2, c1 = (int)qy1f - wt + 2;                        \
            int blt = (r0 + c0) << 7, brb = (r1 + c1) << 7;                              \
            int blb = (r0 + c1) << 7, brt = (r1 + c0) << 7;                              \
            int z0 = ((q4 ^ c0) & 7) << 4, z1 = ((q4 ^ c1) & 7) << 4;                    \
            clo##S[0] = *(const uint4*)(raw + blt + z0);                                 \
            chi##S[0] = *(const uint4*)(raw + blt + (z0 ^ 64));                          \
            clo##S[1] = *(const uint4*)(raw + brb + z1);                                 \
            chi##S[1] = *(const uint4*)(raw + brb + (z1 ^ 64));                          \
            clo##S[2] = *(const uint4*)(raw + blb + z1);                                 \
            chi##S[2] = *(const uint4*)(raw + blb + (z1 ^ 64));                          \
            chi##S[3] = *(const uint4*)(raw + brt + (z0 ^ 64));                          \
            clo##S[3] = *(const uint4*)(raw + brt + z0);                                 \
            gq##S = make_uint4(dup16(ax0 * ay0), dup16(ax1 * ay1),                       \
                               dup16(ax0 * ay1), dup16(ax1 * ay0));                      \
            const _Float16* wn = wmh + ((n) << 12);                                      \
            _Pragma("unroll")                                                            \
            for (int of = 0; of < 4; ++of) {                                             \
                wa##S[2 * of]     = *(const f16x8*)(wn + (((of << 1) + 0) << 9) + lofs); \
                wa##S[2 * of + 1] = *(const f16x8*)(wn + (((of << 1) + 1) << 9) + lofs); \
            }                                                                            \
        }

#define TAPEXEC(S)                                                                       \
        {                                                                                \
            f16x8 bfr0, bfr1;                                                            \
            blend8(clo##S, chi##S, gq##S, bfr0, bfr1);                                   \
            _Pragma("unroll")                                                            \
            for (int of = 0; of < 4; ++of) {                                             \
                acc[of] = MFMAH(wa##S[2 * of],     bfr0, acc[of]);                       \
                acc[of] = MFMAH(wa##S[2 * of + 1], bfr1, acc[of]);                       \
            }                                                                            \
        }

        TAPLOAD(0, A)
        TAPLOAD(1, B) TAPEXEC(A)
        TAPLOAD(2, A) TAPEXEC(B)
        TAPLOAD(3, B) TAPEXEC(A)
        TAPLOAD(4, A) TAPEXEC(B)
        TAPLOAD(5, B) TAPEXEC(A)
        TAPLOAD(6, A) TAPEXEC(B)
        TAPLOAD(7, B) TAPEXEC(A)
        TAPLOAD(8, A) TAPEXEC(B)
                      TAPEXEC(A)
#undef TAPLOAD
#undef TAPEXEC
#undef OXQ
#undef OYQ
    } else {
        // ---- SLOW PATH (rare): all-global gather ----
        for (int n = 0; n < 9; ++n) {
            const int g = n / 3, dj = n % 3;
            float ox = (float)offv[px * 24 + n], oy = (float)offv[px * 24 + 9 + n];
            float pxf = (float)(h + g) + ox, pyf = (float)(wt + px + dj) + oy;
            float fx = floorf(pxf), fy = floorf(pyf);
            float qx0f = fminf(fmaxf(fx, 0.f), 129.f);
            float qx1f = fminf(fmaxf(fx + 1.f, 0.f), 129.f);
            float qy0f = fminf(fmaxf(fy, 0.f), 129.f);
            float qy1f = fminf(fmaxf(fy + 1.f, 0.f), 129.f);
            float pxc = fminf(fmaxf(pxf, 0.f), 129.f);
            float pyc = fminf(fmaxf(pyf, 0.f), 129.f);
            float ax0 = 1.f + (qx0f - pxc), ax1 = 1.f - (qx1f - pxc);
            float ay0 = 1.f + (qy0f - pyc), ay1 = 1.f - (qy1f - pyc);
            int qx[2] = {(int)qx0f, (int)qx1f};
            int qy[2] = {(int)qy0f, (int)qy1f};
            uint4 clo[4], chi[4];
            const int rsel[4] = {0, 1, 0, 1}, csel[4] = {0, 1, 1, 0};
#pragma unroll
            for (int j = 0; j < 4; ++j) {
                int rx = qx[rsel[j]], ry = qy[csel[j]];
                bool v = (rx >= 1) & (rx <= 128) & (ry >= 1) & (ry <= 128);
                clo[j] = make_uint4(0, 0, 0, 0);
                chi[j] = make_uint4(0, 0, 0, 0);
                if (v) {
                    const unsigned short* gp = xtb + ((((size_t)(rx - 1) << 7) + (ry - 1)) << 6);
                    clo[j] = *(const uint4*)(gp + (q4 << 3));
                    chi[j] = *(const uint4*)(gp + (q4 << 3) + 32);
                }
            }
            uint4 gq = make_uint4(dup16(ax0 * ay0), dup16(ax1 * ay1),
                                  dup16(ax0 * ay1), dup16(ax1 * ay0));
            f16x8 bfr0, bfr1;
            blend8(clo, chi, gq, bfr0, bfr1);
            const _Float16* wn = wmh + (n << 12);
#pragma unroll
            for (int of = 0; of < 4; ++of) {
                f16x8 a0 = *(const f16x8*)(wn + (((of << 1) + 0) << 9) + lofs);
                f16x8 a1 = *(const f16x8*)(wn + (((of << 1) + 1) << 9) + lofs);
                acc[of] = MFMAH(a0, bfr0, acc[of]);
                acc[of] = MFMAH(a1, bfr1, acc[of]);
            }
        }
    }

    // ---- Epilogue: + residual ----
#pragma unroll
    for (int of = 0; of < 4; ++of)
#pragma unroll
        for (int rg = 0; rg < 4; ++rg)
            out[obase + (size_t)((of << 4) + (q4 << 2) + rg) * 16384] = acc[of][rg] + xres[of][rg];
}

extern "C" void kernel_launch(void* const* d_in, const int* in_sizes, int n_in,
                              void* d_out, int out_size, void* d_ws, size_t ws_size,
                              hipStream_t stream) {
    const float* x      = (const float*)d_in[0];
    const float* w_off  = (const float*)d_in[1];
    const float* b_off  = (const float*)d_in[2];
    const float* w_conv = (const float*)d_in[3];

    unsigned short* xt    = (unsigned short*)d_ws;
    unsigned short* w_m2  = xt + (size_t)8 * 128 * 128 * 64;
    unsigned short* woff2 = w_m2 + 9 * 64 * 64;

    hipLaunchKernelGGL(k_prep_xt, dim3(1024), dim3(256), 0, stream, x, xt);
    hipLaunchKernelGGL(k_prep_w,  dim3(216),  dim3(256), 0, stream, w_conv, w_off, w_m2, woff2);
    hipLaunchKernelGGL(k_fused,   dim3(2048), dim3(256), 0, stream,
                       x, xt, w_m2, woff2, b_off, (float*)d_out);
}

// Round 10
// 79.380 us; speedup vs baseline: 1.3905x; 1.1539x over previous
//
#include <hip/hip_runtime.h>

// DeformConv2dBlock on gfx950: B=8, C=64, H=W=128, N=9 taps, pad=1.
// R9: weights staged in LDS once per block (kills ~0.9GB/dispatch L2 re-reads),
// full-row blocks (128 px, 8 waves), 4-slot rolling row ring, dynamic 145KB LDS.

typedef _Float16 h2    __attribute__((ext_vector_type(2)));
typedef _Float16 f16x8 __attribute__((ext_vector_type(8)));
typedef float    f32x4 __attribute__((ext_vector_type(4)));

#define MFMAH(a, b, c) __builtin_amdgcn_mfma_f32_16x16x32_f16(a, b, c, 0, 0, 0)

#define RAW_SZ  68608    // 4 slots * 134 recs * 128 B
#define W_OFF   68608
#define W_SZ    73728    // w_m2 fp16 (woff2 fits in first 36864 during Phase A)
#define OFV_OFF 142336
#define SFB_OFF 148480
#define LDS_TOT 148496

__device__ __forceinline__ unsigned short f2h(float f) {
    return __builtin_bit_cast(unsigned short, (_Float16)f);
}
__device__ __forceinline__ float h2f_bits(unsigned u) {
    return (float)__builtin_bit_cast(_Float16, (unsigned short)(u & 0xffffu));
}
__device__ __forceinline__ unsigned dup16(float g) {
    _Float16 t = (_Float16)g;
    h2 r = {t, t};
    return __builtin_bit_cast(unsigned, r);
}

__device__ __forceinline__ void blend8(const uint4* clo, const uint4* chi, uint4 gq,
                                       f16x8& bfr0, f16x8& bfr1) {
    h2 g0 = __builtin_bit_cast(h2, gq.x), g1 = __builtin_bit_cast(h2, gq.y);
    h2 g2 = __builtin_bit_cast(h2, gq.z), g3 = __builtin_bit_cast(h2, gq.w);
    const unsigned* c0 = (const unsigned*)&clo[0];
    const unsigned* c1 = (const unsigned*)&clo[1];
    const unsigned* c2 = (const unsigned*)&clo[2];
    const unsigned* c3 = (const unsigned*)&clo[3];
    const unsigned* e0 = (const unsigned*)&chi[0];
    const unsigned* e1 = (const unsigned*)&chi[1];
    const unsigned* e2 = (const unsigned*)&chi[2];
    const unsigned* e3 = (const unsigned*)&chi[3];
    unsigned owl[4], owh[4];
#pragma unroll
    for (int d = 0; d < 4; ++d) {
        h2 sl = __builtin_bit_cast(h2, c0[d]) * g0;
        sl = __builtin_elementwise_fma(__builtin_bit_cast(h2, c1[d]), g1, sl);
        sl = __builtin_elementwise_fma(__builtin_bit_cast(h2, c2[d]), g2, sl);
        sl = __builtin_elementwise_fma(__builtin_bit_cast(h2, c3[d]), g3, sl);
        owl[d] = __builtin_bit_cast(unsigned, sl);
        h2 sh = __builtin_bit_cast(h2, e0[d]) * g0;
        sh = __builtin_elementwise_fma(__builtin_bit_cast(h2, e1[d]), g1, sh);
        sh = __builtin_elementwise_fma(__builtin_bit_cast(h2, e2[d]), g2, sh);
        sh = __builtin_elementwise_fma(__builtin_bit_cast(h2, e3[d]), g3, sh);
        owh[d] = __builtin_bit_cast(unsigned, sh);
    }
    bfr0 = __builtin_bit_cast(f16x8, *(const uint4*)owl);
    bfr1 = __builtin_bit_cast(f16x8, *(const uint4*)owh);
}

// x[b][c][h][w] f32 -> xt[b][h][w][c] fp16
__global__ __launch_bounds__(256) void k_prep_xt(const float* __restrict__ x,
                                                 unsigned short* __restrict__ xt) {
    __shared__ float xs[64][129];
    const int bh = blockIdx.x;
    const int h = bh & 127, b = bh >> 7;
    const float* xr = x + ((size_t)b * 64 * 128 + h) * 128;
    for (int idx = threadIdx.x; idx < 8192; idx += 256) {
        int c = idx >> 7, w = idx & 127;
        xs[c][w] = xr[(size_t)c * 16384 + w];
    }
    __syncthreads();
    unsigned short* xto = xt + ((size_t)bh << 13);
    for (int j = threadIdx.x; j < 1024; j += 256) {
        int w = j >> 3, c0 = (j & 7) << 3;
        unsigned short tmp[8];
#pragma unroll
        for (int e = 0; e < 8; ++e) tmp[e] = f2h(xs[c0 + e][w]);
        *(uint4*)(xto + w * 64 + c0) = *(const uint4*)tmp;
    }
}

// Fragment-ordered fp16 weights (layout as R3..R8).
__global__ void k_prep_w(const float* __restrict__ w_conv, const float* __restrict__ w_off,
                         unsigned short* __restrict__ w_m2, unsigned short* __restrict__ woff2) {
    int t = blockIdx.x * 256 + threadIdx.x;
    if (t < 36864) {
        int r = t & 511;
        int fid = t >> 9;
        int l15 = r >> 5, q4 = (r >> 3) & 3, e = t & 7;
        int chunk = fid & 1, of = (fid >> 1) & 3, n = fid >> 3;
        int o = of * 16 + l15, c = chunk * 32 + q4 * 8 + e;
        w_m2[t] = f2h(w_conv[(o * 64 + c) * 9 + n]);
    }
    int t2 = t - 36864;
    if (t2 >= 0 && t2 < 18432) {
        int r = t2 & 511;
        int fid = t2 >> 9;
        int l15 = r >> 5, q4 = (r >> 3) & 3, e = t2 & 7;
        int kc = fid & 1, half = (fid >> 1) & 1, rj = fid >> 2;
        int k = half * 16 + l15, c = kc * 32 + q4 * 8 + e;
        woff2[t2] = (k < 18) ? f2h(w_off[(k * 64 + c) * 9 + rj]) : (unsigned short)0;
    }
}

// One block = (b, h): full 128-px row x 64 output channels. 8 waves.
__global__ __launch_bounds__(512, 2) void k_fused(
    const float* __restrict__ x, const unsigned short* __restrict__ xt,
    const unsigned short* __restrict__ w_m2g, const unsigned short* __restrict__ woff2g,
    const float* __restrict__ b_off, float* __restrict__ out) {

    extern __shared__ __align__(16) unsigned char lds[];
    unsigned char* raw  = lds;                              // 4-slot row ring, swizzled
    _Float16*      wlds = (_Float16*)(lds + W_OFF);         // woff2 then w_m2
    _Float16*      offv = (_Float16*)(lds + OFV_OFF);       // [128][24]
    int*           sfbp = (int*)(lds + SFB_OFF);

    const int wk = ((blockIdx.x & 7) << 7) | (blockIdx.x >> 3);   // XCD: one image per XCD
    const int b = wk >> 7, h = wk & 127;

    const int tid  = threadIdx.x;
    const int lane = tid & 63, wid = tid >> 6;
    const int l15  = lane & 15, q4 = lane >> 4;
    const int lofs = ((l15 << 2) + q4) << 3;
    const int px   = wid * 16 + l15;

    const unsigned short* xtb = xt + ((size_t)b << 20);

    if (tid == 0) *sfbp = 0;

    // ---- stage ring rows h-2..h+1 (slot = (row+4)&3) + woff2 into wlds ----
    for (int idx = tid; idx < 4288; idx += 512) {            // 4*134*8
        int rec = idx >> 3, cc = idx & 7;
        int rl = rec / 134, col = rec - rl * 134;
        int xr = h - 2 + rl, xc = col - 3;
        uint4 v = make_uint4(0, 0, 0, 0);
        if (xr >= 0 && xr < 128 && xc >= 0 && xc < 128)
            v = *(const uint4*)(xtb + ((((size_t)xr << 7) + xc) << 6) + (cc << 3));
        int slot = (xr + 4) & 3;
        *(uint4*)(raw + ((slot * 134 + col) << 7) + ((cc ^ (col & 7)) << 4)) = v;
    }
    for (int idx = tid; idx < 2304; idx += 512)              // woff2: 18432 halves
        ((uint4*)wlds)[idx] = ((const uint4*)woff2g)[idx];
    __syncthreads();

    // ---- Phase A: offset conv via fp16 MFMA (weights + window from LDS), pipelined ----
    {
        f32x4 o0a = {0,0,0,0}, o0b = {0,0,0,0}, o1a = {0,0,0,0}, o1b = {0,0,0,0};
        f16x8 bfgA, af0A, af1A, bfgB, af0B, af1B;

#define ALOAD(s, S)                                                                      \
        {                                                                                \
            constexpr int rj = (s) >> 1, kc = (s) & 1;                                   \
            const int colw = px + (rj % 3) + 2;                                          \
            const int slt  = (h + (rj / 3) + 3) & 3;                                     \
            bfg##S = *(const f16x8*)(raw + ((slt * 134 + colw) << 7) + ((((kc << 2) + q4) ^ (colw & 7)) << 4)); \
            af0##S = *(const f16x8*)(wlds + ((((rj * 2 + 0) << 1) + kc) << 9) + lofs);   \
            af1##S = *(const f16x8*)(wlds + ((((rj * 2 + 1) << 1) + kc) << 9) + lofs);   \
        }
#define AEXEC(S, P)                                                                      \
        {                                                                                \
            o0##P = MFMAH(af0##S, bfg##S, o0##P);                                        \
            o1##P = MFMAH(af1##S, bfg##S, o1##P);                                        \
        }
        ALOAD(0, A)
        ALOAD(1, B)  AEXEC(A, a)
        ALOAD(2, A)  AEXEC(B, b)
        ALOAD(3, B)  AEXEC(A, a)
        ALOAD(4, A)  AEXEC(B, b)
        ALOAD(5, B)  AEXEC(A, a)
        ALOAD(6, A)  AEXEC(B, b)
        ALOAD(7, B)  AEXEC(A, a)
        ALOAD(8, A)  AEXEC(B, b)
        ALOAD(9, B)  AEXEC(A, a)
        ALOAD(10, A) AEXEC(B, b)
        ALOAD(11, B) AEXEC(A, a)
        ALOAD(12, A) AEXEC(B, b)
        ALOAD(13, B) AEXEC(A, a)
        ALOAD(14, A) AEXEC(B, b)
        ALOAD(15, B) AEXEC(A, a)
        ALOAD(16, A) AEXEC(B, b)
        ALOAD(17, B) AEXEC(A, a)
                     AEXEC(B, b)
#undef ALOAD
#undef AEXEC
        float4 bo = *(const float4*)(b_off + (q4 << 2));
        float2 bo2 = *(const float2*)(b_off + 16);
        const float bov[4] = {bo.x, bo.y, bo.z, bo.w};
#pragma unroll
        for (int rg = 0; rg < 4; ++rg) {
            int o = (q4 << 2) + rg;
            offv[px * 24 + o] = (_Float16)(o0a[rg] + o0b[rg] + bov[rg]);
            if (q4 == 0 && rg < 2)
                offv[px * 24 + 16 + rg] = (_Float16)(o1a[rg] + o1b[rg] + (rg ? bo2.y : bo2.x));
        }
    }
    __syncthreads();   // offv ready; wlds reads done

    // ---- stage w_m2 into wlds + B-lite row check + residual prefetch ----
    for (int idx = tid; idx < 4608; idx += 512)              // 36864 halves
        ((uint4*)wlds)[idx] = ((const uint4*)w_m2g)[idx];
    for (int idx = tid; idx < 1152; idx += 512) {            // 128 px * 9 taps
        int n = idx % 9, p = idx / 9;
        int g = n / 3;
        float ox = (float)offv[p * 24 + n];
        float pxf = (float)(h + g) + ox;
        float fx = floorf(pxf);
        int t0 = (int)fminf(fmaxf(fx, 0.f), 129.f) + 1 - h - g;
        int t1 = (int)fminf(fmaxf(fx + 1.f, 0.f), 129.f) + 1 - h - g;
        if (((unsigned)t0 > 3u) | ((unsigned)t1 > 3u)) *sfbp = 1;
    }
    const size_t obase = ((size_t)b << 20) + h * 128 + px;
    float xres[4][4];
#pragma unroll
    for (int of = 0; of < 4; ++of)
#pragma unroll
        for (int rg = 0; rg < 4; ++rg)
            xres[of][rg] = x[obase + (size_t)((of << 4) + (q4 << 2) + rg) * 16384];
    __syncthreads();   // wlds = w_m2 ready; sfb final
    const bool slow = (*sfbp != 0);

    f32x4 acc[4];
#pragma unroll
    for (int of = 0; of < 4; ++of) acc[of] = (f32x4){0.f, 0.f, 0.f, 0.f};

    if (!slow) {
        // ---- preload my pixel's 18 offsets to const-indexed regs ----
        const unsigned* op = (const unsigned*)(offv + px * 24);
        uint4 oA = *(const uint4*)op;
        uint4 oB = *(const uint4*)(op + 4);
        unsigned oC = op[8];
        const unsigned owr[9] = {oA.x, oA.y, oA.z, oA.w, oB.x, oB.y, oB.z, oB.w, oC};
#define OXQ(n) h2f_bits(owr[(n) >> 1] >> (((n) & 1) << 4))
#define OYQ(n) h2f_bits(owr[(9 + (n)) >> 1] >> (((9 + (n)) & 1) << 4))

        uint4 cloA[4], chiA[4], cloB[4], chiB[4];
        uint4 gqA, gqB;
        f16x8 waA[8], waB[8];
        uint4 pf[3];
        int prec[3], pcc[3];

#define PREF(ROW)                                                                        \
        {                                                                                \
            _Pragma("unroll")                                                            \
            for (int k = 0; k < 3; ++k) {                                                \
                int idx = tid + (k << 9);                                                \
                bool v = idx < 1072;                                                     \
                int rec = idx >> 3;                                                      \
                pcc[k] = idx & 7;                                                        \
                int xc = rec - 3;                                                        \
                uint4 vv = make_uint4(0, 0, 0, 0);                                       \
                if (v && (ROW) < 128 && xc >= 0 && xc < 128)                             \
                    vv = *(const uint4*)(xtb + ((((size_t)(ROW) << 7) + xc) << 6) + (pcc[k] << 3)); \
                prec[k] = v ? rec : -1;                                                  \
                pf[k] = vv;                                                              \
            }                                                                            \
        }
#define WRB(ROW)                                                                         \
        {                                                                                \
            const int slt = ((ROW) + 4) & 3;                                             \
            _Pragma("unroll")                                                            \
            for (int k = 0; k < 3; ++k)                                                  \
                if (prec[k] >= 0)                                                        \
                    *(uint4*)(raw + ((slt * 134 + prec[k]) << 7) + ((pcc[k] ^ (prec[k] & 7)) << 4)) = pf[k]; \
        }

#define TAPLOAD(n, S)                                                                    \
        {                                                                                \
            constexpr int g = (n) / 3, dj = (n) % 3;                                     \
            float ox = OXQ(n), oy = OYQ(n);                                              \
            float pxf = (float)(h + g) + ox, pyf = (float)(px + dj) + oy;                \
            float fx = floorf(pxf), fy = floorf(pyf);                                    \
            float qx0f = fminf(fmaxf(fx, 0.f), 129.f);                                   \
            float qx1f = fminf(fmaxf(fx + 1.f, 0.f), 129.f);                             \
            float qy0f = fminf(fmaxf(fy, 0.f), 129.f);                                   \
            float qy1f = fminf(fmaxf(fy + 1.f, 0.f), 129.f);                             \
            float pxc = fminf(fmaxf(pxf, 0.f), 129.f);                                   \
            float pyc = fminf(fmaxf(pyf, 0.f), 129.f);                                   \
            float ax0 = 1.f + (qx0f - pxc), ax1 = 1.f - (qx1f - pxc);                    \
            float ay0 = 1.f + (qy0f - pyc), ay1 = 1.f - (qy1f - pyc);                    \
            int r0 = (((int)qx0f + 3) & 3) * 134, r1 = (((int)qx1f + 3) & 3) * 134;      \
            int c0 = (int)qy0f + 2, c1 = (int)qy1f + 2;                                  \
            int blt = (r0 + c0) << 7, brb = (r1 + c1) << 7;                              \
            int blb = (r0 + c1) << 7, brt = (r1 + c0) << 7;                              \
            int z0 = ((q4 ^ c0) & 7) << 4, z1 = ((q4 ^ c1) & 7) << 4;                    \
            clo##S[0] = *(const uint4*)(raw + blt + z0);                                 \
            chi##S[0] = *(const uint4*)(raw + blt + (z0 ^ 64));                          \
            clo##S[1] = *(const uint4*)(raw + brb + z1);                                 \
            chi##S[1] = *(const uint4*)(raw + brb + (z1 ^ 64));                          \
            clo##S[2] = *(const uint4*)(raw + blb + z1);                                 \
            chi##S[2] = *(const uint4*)(raw + blb + (z1 ^ 64));                          \
            clo##S[3] = *(const uint4*)(raw + brt + z0);                                 \
            chi##S[3] = *(const uint4*)(raw + brt + (z0 ^ 64));                          \
            gq##S = make_uint4(dup16(ax0 * ay0), dup16(ax1 * ay1),                       \
                               dup16(ax0 * ay1), dup16(ax1 * ay0));                      \
            _Pragma("unroll")                                                            \
            for (int of = 0; of < 4; ++of) {                                             \
                wa##S[2 * of]     = *(const f16x8*)(wlds + (((n) * 8 + of * 2 + 0) << 9) + lofs); \
                wa##S[2 * of + 1] = *(const f16x8*)(wlds + (((n) * 8 + of * 2 + 1) << 9) + lofs); \
            }                                                                            \
        }
#define TAPEXEC(S)                                                                       \
        {                                                                                \
            f16x8 bfr0, bfr1;                                                            \
            blend8(clo##S, chi##S, gq##S, bfr0, bfr1);                                   \
            _Pragma("unroll")                                                            \
            for (int of = 0; of < 4; ++of) {                                             \
                acc[of] = MFMAH(wa##S[2 * of],     bfr0, acc[of]);                       \
                acc[of] = MFMAH(wa##S[2 * of + 1], bfr1, acc[of]);                       \
            }                                                                            \
        }

        PREF(h + 2)
        TAPLOAD(0, A)
        TAPLOAD(1, B) TAPEXEC(A)
        TAPLOAD(2, A) TAPEXEC(B)
                      TAPEXEC(A)
        __syncthreads();
        WRB(h + 2)
        __syncthreads();
        PREF(h + 3)
        TAPLOAD(3, A)
        TAPLOAD(4, B) TAPEXEC(A)
        TAPLOAD(5, A) TAPEXEC(B)
                      TAPEXEC(A)
        __syncthreads();
        WRB(h + 3)
        __syncthreads();
        TAPLOAD(6, A)
        TAPLOAD(7, B) TAPEXEC(A)
        TAPLOAD(8, A) TAPEXEC(B)
                      TAPEXEC(A)
#undef TAPLOAD
#undef TAPEXEC
#undef PREF
#undef WRB
#undef OXQ
#undef OYQ
    } else {
        // ---- SLOW PATH (rare): all-global gather; weights from LDS ----
        for (int n = 0; n < 9; ++n) {
            const int g = n / 3, dj = n % 3;
            float ox = (float)offv[px * 24 + n], oy = (float)offv[px * 24 + 9 + n];
            float pxf = (float)(h + g) + ox, pyf = (float)(px + dj) + oy;
            float fx = floorf(pxf), fy = floorf(pyf);
            float qx0f = fminf(fmaxf(fx, 0.f), 129.f);
            float qx1f = fminf(fmaxf(fx + 1.f, 0.f), 129.f);
            float qy0f = fminf(fmaxf(fy, 0.f), 129.f);
            float qy1f = fminf(fmaxf(fy + 1.f, 0.f), 129.f);
            float pxc = fminf(fmaxf(pxf, 0.f), 129.f);
            float pyc = fminf(fmaxf(pyf, 0.f), 129.f);
            float ax0 = 1.f + (qx0f - pxc), ax1 = 1.f - (qx1f - pxc);
            float ay0 = 1.f + (qy0f - pyc), ay1 = 1.f - (qy1f - pyc);
            int qx[2] = {(int)qx0f, (int)qx1f};
            int qy[2] = {(int)qy0f, (int)qy1f};
            uint4 clo[4], chi[4];
            const int rsel[4] = {0, 1, 0, 1}, csel[4] = {0, 1, 1, 0};
#pragma unroll
            for (int j = 0; j < 4; ++j) {
                int rx = qx[rsel[j]], ry = qy[csel[j]];
                bool v = (rx >= 1) & (rx <= 128) & (ry >= 1) & (ry <= 128);
                clo[j] = make_uint4(0, 0, 0, 0);
                chi[j] = make_uint4(0, 0, 0, 0);
                if (v) {
                    const unsigned short* gp = xtb + ((((size_t)(rx - 1) << 7) + (ry - 1)) << 6);
                    clo[j] = *(const uint4*)(gp + (q4 << 3));
                    chi[j] = *(const uint4*)(gp + (q4 << 3) + 32);
                }
            }
            uint4 gq = make_uint4(dup16(ax0 * ay0), dup16(ax1 * ay1),
                                  dup16(ax0 * ay1), dup16(ax1 * ay0));
            f16x8 bfr0, bfr1;
            blend8(clo, chi, gq, bfr0, bfr1);
#pragma unroll
            for (int of = 0; of < 4; ++of) {
                f16x8 a0 = *(const f16x8*)(wlds + ((n * 8 + of * 2 + 0) << 9) + lofs);
                f16x8 a1 = *(const f16x8*)(wlds + ((n * 8 + of * 2 + 1) << 9) + lofs);
                acc[of] = MFMAH(a0, bfr0, acc[of]);
                acc[of] = MFMAH(a1, bfr1, acc[of]);
            }
        }
    }

    // ---- Epilogue: + residual ----
#pragma unroll
    for (int of = 0; of < 4; ++of)
#pragma unroll
        for (int rg = 0; rg < 4; ++rg)
            out[obase + (size_t)((of << 4) + (q4 << 2) + rg) * 16384] = acc[of][rg] + xres[of][rg];
}

extern "C" void kernel_launch(void* const* d_in, const int* in_sizes, int n_in,
                              void* d_out, int out_size, void* d_ws, size_t ws_size,
                              hipStream_t stream) {
    const float* x      = (const float*)d_in[0];
    const float* w_off  = (const float*)d_in[1];
    const float* b_off  = (const float*)d_in[2];
    const float* w_conv = (const float*)d_in[3];

    unsigned short* xt    = (unsigned short*)d_ws;
    unsigned short* w_m2  = xt + (size_t)8 * 128 * 128 * 64;
    unsigned short* woff2 = w_m2 + 9 * 64 * 64;

    hipFuncSetAttribute((const void*)k_fused,
                        hipFuncAttributeMaxDynamicSharedMemorySize, LDS_TOT);

    hipLaunchKernelGGL(k_prep_xt, dim3(1024), dim3(256), 0, stream, x, xt);
    hipLaunchKernelGGL(k_prep_w,  dim3(216),  dim3(256), 0, stream, w_conv, w_off, w_m2, woff2);
    hipLaunchKernelGGL(k_fused,   dim3(1024), dim3(512), LDS_TOT, stream,
                       x, xt, w_m2, woff2, b_off, (float*)d_out);
}